// Round 1
// baseline (392.851 us; speedup 1.0000x reference)
//
#include <hip/hip_runtime.h>
#include <hip/hip_bf16.h>

#define S_DIM 256
#define I_DIM 512
#define NROWS (S_DIM * I_DIM)  // 131072

using bf16x8 = __attribute__((ext_vector_type(8))) short;
using f32x4  = __attribute__((ext_vector_type(4))) float;
typedef unsigned short ushort_t;

__device__ __forceinline__ unsigned short f2bf(float f) {
  unsigned int u = __builtin_bit_cast(unsigned int, f);
  u += 0x7fffu + ((u >> 16) & 1u);   // RNE
  return (unsigned short)(u >> 16);
}
__device__ __forceinline__ float bf2f(unsigned short u) {
  unsigned int x = ((unsigned int)u) << 16;
  return __builtin_bit_cast(float, x);
}
// async global->LDS, 16 B per lane; LDS dst = wave-uniform base + lane*16
__device__ __forceinline__ void gl_lds16(const void* g, void* l) {
  __builtin_amdgcn_global_load_lds(
      (const __attribute__((address_space(1))) void*)g,
      (__attribute__((address_space(3))) void*)l, 16, 0, 0);
}

// ---------------------------------------------------------------------------
// K0: cast+transpose weights to bf16.
// ---------------------------------------------------------------------------
__global__ __launch_bounds__(256) void prep_weights(
    const float* __restrict__ Wk, const float* __restrict__ Wv,
    const float* __restrict__ Wg, const float* __restrict__ Wo,
    ushort_t* __restrict__ WkvT, ushort_t* __restrict__ WgT,
    ushort_t* __restrict__ WoT) {
  int t = blockIdx.x * 256 + threadIdx.x;       // 65536 threads
  int n = t >> 8, c = t & 255;
  if (t < 64 * 256) {
    float v = (n < 32) ? Wk[c * 32 + n] : Wv[c * 32 + (n - 32)];
    WkvT[t] = f2bf(v);
  }
  WgT[t] = f2bf(Wg[c * 256 + n]);
  WoT[t] = f2bf(Wo[c * 256 + n]);
}

// ---------------------------------------------------------------------------
// K1: LayerNorm -> xn (bf16) + per-block partial column sums (NO atomics).
// Block b: i = b&511, sq = b>>9; wave w handles s = sq*64 + w*16 + it.
// ---------------------------------------------------------------------------
__global__ __launch_bounds__(256) void ln_kernel(
    const float* __restrict__ x, const float* __restrict__ gamma,
    const float* __restrict__ beta, ushort_t* __restrict__ xn,
    float* __restrict__ xpart) {
  __shared__ float sacc[4][256];
  int b = blockIdx.x;                  // 2048
  int i = b & (I_DIM - 1);
  int sq = b >> 9;                     // 0..3
  int w = threadIdx.x >> 6;
  int lane = threadIdx.x & 63;

  float4 gv = *(const float4*)(gamma + lane * 4);
  float4 bv = *(const float4*)(beta + lane * 4);
  float p0 = 0.f, p1 = 0.f, p2 = 0.f, p3 = 0.f;

#pragma unroll 4
  for (int it = 0; it < 16; ++it) {
    int s = sq * 64 + w * 16 + it;
    size_t row = (size_t)s * I_DIM + i;
    float4 xv = *(const float4*)(x + row * 256 + lane * 4);
    float sum = xv.x + xv.y + xv.z + xv.w;
    float sq2 = xv.x*xv.x + xv.y*xv.y + xv.z*xv.z + xv.w*xv.w;
#pragma unroll
    for (int off = 32; off >= 1; off >>= 1) {
      sum += __shfl_xor(sum, off);
      sq2 += __shfl_xor(sq2, off);
    }
    float mu = sum * (1.f / 256.f);
    float rs = rsqrtf(sq2 * (1.f / 256.f) - mu * mu + 1e-5f);
    float y0 = (xv.x - mu) * rs * gv.x + bv.x;
    float y1 = (xv.y - mu) * rs * gv.y + bv.y;
    float y2 = (xv.z - mu) * rs * gv.z + bv.z;
    float y3 = (xv.w - mu) * rs * gv.w + bv.w;
    ushort4 o;
    o.x = f2bf(y0); o.y = f2bf(y1); o.z = f2bf(y2); o.w = f2bf(y3);
    *(ushort4*)(xn + row * 256 + lane * 4) = o;
    p0 += y0; p1 += y1; p2 += y2; p3 += y3;
  }
  sacc[w][lane * 4 + 0] = p0;
  sacc[w][lane * 4 + 1] = p1;
  sacc[w][lane * 4 + 2] = p2;
  sacc[w][lane * 4 + 3] = p3;
  __syncthreads();
  int tid = threadIdx.x;
  xpart[((size_t)sq * I_DIM + i) * 256 + tid] =
      sacc[0][tid] + sacc[1][tid] + sacc[2][tid] + sacc[3][tid];
}

// ---------------------------------------------------------------------------
// K2: Q[i][col] = mean_s(xn) @ Wq * (1/sqrt(D)); reduces the 4 partials.
// ---------------------------------------------------------------------------
__global__ __launch_bounds__(256) void q_kernel(
    const float* __restrict__ xpart, const float* __restrict__ Wq,
    float* __restrict__ Q) {
  int i = blockIdx.x, col = threadIdx.x;
  __shared__ float xr[256];
  float s = xpart[((size_t)0 * I_DIM + i) * 256 + col]
          + xpart[((size_t)1 * I_DIM + i) * 256 + col]
          + xpart[((size_t)2 * I_DIM + i) * 256 + col]
          + xpart[((size_t)3 * I_DIM + i) * 256 + col];
  xr[col] = s * (1.f / 256.f);
  __syncthreads();
  float acc = 0.f;
#pragma unroll 8
  for (int c = 0; c < 256; ++c) acc = fmaf(xr[c], Wq[c * 256 + col], acc);
  Q[i * 256 + col] = acc * 0.17677669529663687f;   // 1/sqrt(32)
}

// ---------------------------------------------------------------------------
// K3: KV[row][0:64] = xn[row] @ [Wk|Wv], bf16 output. 64-row tile, 4 waves.
// ---------------------------------------------------------------------------
__global__ __launch_bounds__(256) void kv_kernel(
    const ushort_t* __restrict__ xn, const ushort_t* __restrict__ WkvT,
    ushort_t* __restrict__ KVb) {
  __shared__ __attribute__((aligned(16))) ushort_t xs[64 * 264];
  __shared__ __attribute__((aligned(16))) ushort_t wt[64 * 264];
  int tid = threadIdx.x;
  int m0 = blockIdx.x * 64;

  const uint4* xg = (const uint4*)(xn + (size_t)m0 * 256);
#pragma unroll
  for (int j = 0; j < 8; ++j) {
    int idx = tid + j * 256;
    *(uint4*)(&xs[(idx >> 5) * 264 + (idx & 31) * 8]) = xg[idx];
  }
  const uint4* wg_ = (const uint4*)WkvT;
#pragma unroll
  for (int j = 0; j < 8; ++j) {
    int idx = tid + j * 256;
    *(uint4*)(&wt[(idx >> 5) * 264 + (idx & 31) * 8]) = wg_[idx];
  }
  __syncthreads();

  int w = tid >> 6, lane = tid & 63;
  int m15 = lane & 15, q = lane >> 4;
  f32x4 acc[4] = {};
#pragma unroll
  for (int k = 0; k < 8; ++k) {
    bf16x8 a = *(const bf16x8*)(&xs[(w * 16 + m15) * 264 + k * 32 + q * 8]);
#pragma unroll
    for (int nt = 0; nt < 4; ++nt) {
      bf16x8 bb = *(const bf16x8*)(&wt[(nt * 16 + m15) * 264 + k * 32 + q * 8]);
      acc[nt] = __builtin_amdgcn_mfma_f32_16x16x32_bf16(a, bb, acc[nt], 0, 0, 0);
    }
  }
#pragma unroll
  for (int nt = 0; nt < 4; ++nt)
#pragma unroll
    for (int r = 0; r < 4; ++r)
      KVb[(size_t)(m0 + w * 16 + q * 4 + r) * 64 + nt * 16 + m15] = f2bf(acc[nt][r]);
}

// ---------------------------------------------------------------------------
// K4: attention per residue i. K stays in registers; only V staged to LDS.
// ---------------------------------------------------------------------------
__global__ __launch_bounds__(256) void attn_kernel(
    const ushort_t* __restrict__ KVb, const float* __restrict__ Q,
    float* __restrict__ weighted) {
  __shared__ ushort_t Vs[256 * 36];    // stride 36 shorts: b64-aligned, 2-way banks
  __shared__ float sl[8 * 264];
  __shared__ float ql[256];
  int i = blockIdx.x, tid = threadIdx.x;

  ql[tid] = Q[i * 256 + tid];
  const uint4* src = (const uint4*)(KVb + ((size_t)tid * I_DIM + i) * 64);
  uint4 kr0 = src[0], kr1 = src[1], kr2 = src[2], kr3 = src[3];
#pragma unroll
  for (int j = 0; j < 4; ++j) {
    uint4 v = src[4 + j];
    *(ushort4*)(&Vs[tid * 36 + j * 8 + 0]) = *(ushort4*)&v.x;
    *(ushort4*)(&Vs[tid * 36 + j * 8 + 4]) = *(ushort4*)&v.z;
  }
  // unpack K to fp32
  ushort_t ks[32];
  *(uint4*)&ks[0] = kr0; *(uint4*)&ks[8] = kr1;
  *(uint4*)&ks[16] = kr2; *(uint4*)&ks[24] = kr3;
  float kf[32];
#pragma unroll
  for (int d = 0; d < 32; ++d) kf[d] = bf2f(ks[d]);
  __syncthreads();

#pragma unroll
  for (int h = 0; h < 8; ++h) {
    float sc = 0.f;
#pragma unroll
    for (int d = 0; d < 32; ++d) sc = fmaf(kf[d], ql[h * 32 + d], sc);
    sl[h * 264 + tid] = sc;
  }
  __syncthreads();

  int w = tid >> 6, lane = tid & 63;
#pragma unroll
  for (int hh = 0; hh < 2; ++hh) {
    int h = w * 2 + hh;
    float v0 = sl[h * 264 + lane], v1 = sl[h * 264 + lane + 64];
    float v2 = sl[h * 264 + lane + 128], v3 = sl[h * 264 + lane + 192];
    float m = fmaxf(fmaxf(v0, v1), fmaxf(v2, v3));
#pragma unroll
    for (int off = 32; off >= 1; off >>= 1) m = fmaxf(m, __shfl_xor(m, off));
    float e0 = __expf(v0 - m), e1 = __expf(v1 - m);
    float e2 = __expf(v2 - m), e3 = __expf(v3 - m);
    float ssum = e0 + e1 + e2 + e3;
#pragma unroll
    for (int off = 32; off >= 1; off >>= 1) ssum += __shfl_xor(ssum, off);
    float inv = 1.f / ssum;
    sl[h * 264 + lane] = e0 * inv;
    sl[h * 264 + lane + 64] = e1 * inv;
    sl[h * 264 + lane + 128] = e2 * inv;
    sl[h * 264 + lane + 192] = e3 * inv;
  }
  __syncthreads();

  int h = tid >> 5, d = tid & 31;
  float acc = 0.f;
#pragma unroll 4
  for (int t = 0; t < 256; ++t)
    acc = fmaf(sl[h * 264 + t], bf2f(Vs[t * 36 + d]), acc);
  weighted[i * 256 + tid] = acc;
}

// ---------------------------------------------------------------------------
// K5a: val = sigmoid(xn@Wg + bg) * weighted, bf16, written IN PLACE over xn.
// 128-row tile, 512 threads (8 waves = 2 rowgrp x 4 colgrp, 64x64 per wave).
// BN=256 (full width) so each row strip is owned by exactly one block ->
// in-place overwrite of xn is race-free (xn has no later consumer).
// LDS: As 16K + Bs 32K = 48 KB -> 2 blocks/CU at 88 VGPR (4 waves/SIMD),
// double the occupancy of the old 112-KB fused kernel.
// ---------------------------------------------------------------------------
__global__ __launch_bounds__(512) void gate_val_kernel(
    ushort_t* xv,                       // xn in, val out (same buffer; no restrict)
    const ushort_t* __restrict__ WgT, const float* __restrict__ weighted,
    const float* __restrict__ bg) {
  __shared__ __attribute__((aligned(16))) ushort_t As[128 * 64];
  __shared__ __attribute__((aligned(16))) ushort_t Bs[256 * 64];
  const int tid = threadIdx.x;
  const int m0 = blockIdx.x * 128;
  const int w = tid >> 6, lane = tid & 63;
  const int m15 = lane & 15, q = lane >> 4;
  const int r2 = w >> 2, c4 = w & 3;

  f32x4 acc[4][4];
  const f32x4 zero = {0.f, 0.f, 0.f, 0.f};
#pragma unroll
  for (int t = 0; t < 4; ++t)
#pragma unroll
    for (int nt = 0; nt < 4; ++nt) acc[t][nt] = zero;

#pragma unroll 1
  for (int kc = 0; kc < 4; ++kc) {
    __syncthreads();
    // stage A chunk: 128 rows x 8 units (16 B) = 1024 units
#pragma unroll
    for (int it = 0; it < 2; ++it) {
      int L = it * 512 + tid;
      int r = L >> 3, u = (L & 7) ^ (r & 7);
      gl_lds16(xv + (size_t)(m0 + r) * 256 + kc * 64 + u * 8,
               &As[(it * 512 + w * 64) * 8]);
    }
    // stage B chunk: 256 rows x 8 units = 2048 units
#pragma unroll
    for (int it = 0; it < 4; ++it) {
      int L = it * 512 + tid;
      int n = L >> 3, u = (L & 7) ^ (n & 7);
      gl_lds16(WgT + (size_t)n * 256 + kc * 64 + u * 8,
               &Bs[(it * 512 + w * 64) * 8]);
    }
    __syncthreads();
#pragma unroll
    for (int kk = 0; kk < 2; ++kk) {
      bf16x8 bf[4], af[4];
#pragma unroll
      for (int nt = 0; nt < 4; ++nt) {
        int n = c4 * 64 + nt * 16 + m15;
        bf[nt] = *(const bf16x8*)&Bs[n * 64 + (((kk * 4 + q) ^ (n & 7)) * 8)];
      }
#pragma unroll
      for (int t = 0; t < 4; ++t) {
        int m = r2 * 64 + t * 16 + m15;
        af[t] = *(const bf16x8*)&As[m * 64 + (((kk * 4 + q) ^ (m & 7)) * 8)];
      }
#pragma unroll
      for (int t = 0; t < 4; ++t)
#pragma unroll
        for (int nt = 0; nt < 4; ++nt)
          acc[t][nt] = __builtin_amdgcn_mfma_f32_16x16x32_bf16(af[t], bf[nt], acc[t][nt], 0, 0, 0);
    }
  }

  // epilogue: sigmoid gate * weighted -> val (in place over xn)
#pragma unroll
  for (int nt = 0; nt < 4; ++nt) {
    int col = c4 * 64 + nt * 16 + m15;
    float bgi = bg[col];
#pragma unroll
    for (int t = 0; t < 4; ++t)
#pragma unroll
      for (int r = 0; r < 4; ++r) {
        int row = r2 * 64 + t * 16 + q * 4 + r;
        float pre = acc[t][nt][r] + bgi;
        float g = 1.f / (1.f + __expf(-pre));
        float vv = g * weighted[(size_t)((m0 + row) & (I_DIM - 1)) * 256 + col];
        xv[(size_t)(m0 + row) * 256 + col] = f2bf(vv);
      }
  }
}

// ---------------------------------------------------------------------------
// K5b: out = val @ Wo + bo (f32). Same structure as K5a, different epilogue.
// val is the 64 MB bf16 buffer just written by K5a -> L3-resident read.
// ---------------------------------------------------------------------------
__global__ __launch_bounds__(512) void out_kernel(
    const ushort_t* __restrict__ val, const ushort_t* __restrict__ WoT,
    const float* __restrict__ bo, float* __restrict__ out) {
  __shared__ __attribute__((aligned(16))) ushort_t As[128 * 64];
  __shared__ __attribute__((aligned(16))) ushort_t Bs[256 * 64];
  const int tid = threadIdx.x;
  const int m0 = blockIdx.x * 128;
  const int w = tid >> 6, lane = tid & 63;
  const int m15 = lane & 15, q = lane >> 4;
  const int r2 = w >> 2, c4 = w & 3;

  f32x4 acc[4][4];
  const f32x4 zero = {0.f, 0.f, 0.f, 0.f};
#pragma unroll
  for (int t = 0; t < 4; ++t)
#pragma unroll
    for (int nt = 0; nt < 4; ++nt) acc[t][nt] = zero;

#pragma unroll 1
  for (int kc = 0; kc < 4; ++kc) {
    __syncthreads();
#pragma unroll
    for (int it = 0; it < 2; ++it) {
      int L = it * 512 + tid;
      int r = L >> 3, u = (L & 7) ^ (r & 7);
      gl_lds16(val + (size_t)(m0 + r) * 256 + kc * 64 + u * 8,
               &As[(it * 512 + w * 64) * 8]);
    }
#pragma unroll
    for (int it = 0; it < 4; ++it) {
      int L = it * 512 + tid;
      int n = L >> 3, u = (L & 7) ^ (n & 7);
      gl_lds16(WoT + (size_t)n * 256 + kc * 64 + u * 8,
               &Bs[(it * 512 + w * 64) * 8]);
    }
    __syncthreads();
#pragma unroll
    for (int kk = 0; kk < 2; ++kk) {
      bf16x8 bf[4], af[4];
#pragma unroll
      for (int nt = 0; nt < 4; ++nt) {
        int n = c4 * 64 + nt * 16 + m15;
        bf[nt] = *(const bf16x8*)&Bs[n * 64 + (((kk * 4 + q) ^ (n & 7)) * 8)];
      }
#pragma unroll
      for (int t = 0; t < 4; ++t) {
        int m = r2 * 64 + t * 16 + m15;
        af[t] = *(const bf16x8*)&As[m * 64 + (((kk * 4 + q) ^ (m & 7)) * 8)];
      }
#pragma unroll
      for (int t = 0; t < 4; ++t)
#pragma unroll
        for (int nt = 0; nt < 4; ++nt)
          acc[t][nt] = __builtin_amdgcn_mfma_f32_16x16x32_bf16(af[t], bf[nt], acc[t][nt], 0, 0, 0);
    }
  }

  // epilogue: out = acc + bo (f32, coalesced 64-B segments per 16 lanes)
#pragma unroll
  for (int nt = 0; nt < 4; ++nt) {
    int col = c4 * 64 + nt * 16 + m15;
    float boi = bo[col];
#pragma unroll
    for (int t = 0; t < 4; ++t)
#pragma unroll
      for (int r = 0; r < 4; ++r) {
        int row = r2 * 64 + t * 16 + q * 4 + r;
        out[(size_t)(m0 + row) * 256 + col] = acc[t][nt][r] + boi;
      }
  }
}

// ---------------------------------------------------------------------------
extern "C" void kernel_launch(void* const* d_in, const int* in_sizes, int n_in,
                              void* d_out, int out_size, void* d_ws, size_t ws_size,
                              hipStream_t stream) {
  const float* msa = (const float*)d_in[0];
  const float* gam = (const float*)d_in[1];
  const float* bet = (const float*)d_in[2];
  const float* Wq  = (const float*)d_in[3];
  const float* Wk  = (const float*)d_in[4];
  const float* Wv  = (const float*)d_in[5];
  const float* Wg  = (const float*)d_in[6];
  const float* bg  = (const float*)d_in[7];
  const float* Wo  = (const float*)d_in[8];
  const float* bo  = (const float*)d_in[9];
  float* out = (float*)d_out;

  char* ws = (char*)d_ws;
  ushort_t* xn     = (ushort_t*)ws;                    // 67,108,864 B (xn, then val in-place)
  float* xpart     = (float*)(ws + 67108864);          //  2,097,152 B
  float* Q         = (float*)(ws + 69206016);          //    524,288 B
  ushort_t* KVb    = (ushort_t*)(ws + 69730304);       // 16,777,216 B
  float* weighted  = (float*)(ws + 86507520);          //    524,288 B
  ushort_t* WkvT   = (ushort_t*)(ws + 87031808);       //     32,768 B
  ushort_t* WgT    = (ushort_t*)(ws + 87064576);       //    131,072 B
  ushort_t* WoT    = (ushort_t*)(ws + 87195648);       //    131,072 B

  prep_weights<<<256, 256, 0, stream>>>(Wk, Wv, Wg, Wo, WkvT, WgT, WoT);
  ln_kernel<<<2048, 256, 0, stream>>>(msa, gam, bet, xn, xpart);
  q_kernel<<<512, 256, 0, stream>>>(xpart, Wq, Q);
  kv_kernel<<<2048, 256, 0, stream>>>(xn, WkvT, KVb);
  attn_kernel<<<512, 256, 0, stream>>>(KVb, Q, weighted);
  gate_val_kernel<<<1024, 512, 0, stream>>>(xn, WgT, weighted, bg);
  out_kernel<<<1024, 512, 0, stream>>>(xn, WoT, bo, out);
}

// Round 2
// 371.723 us; speedup vs baseline: 1.0568x; 1.0568x over previous
//
#include <hip/hip_runtime.h>
#include <hip/hip_bf16.h>

#define S_DIM 256
#define I_DIM 512
#define NROWS (S_DIM * I_DIM)  // 131072

using bf16x8 = __attribute__((ext_vector_type(8))) short;
using f32x4  = __attribute__((ext_vector_type(4))) float;
typedef unsigned short ushort_t;

__device__ __forceinline__ unsigned short f2bf(float f) {
  unsigned int u = __builtin_bit_cast(unsigned int, f);
  u += 0x7fffu + ((u >> 16) & 1u);   // RNE
  return (unsigned short)(u >> 16);
}
__device__ __forceinline__ float bf2f(unsigned short u) {
  unsigned int x = ((unsigned int)u) << 16;
  return __builtin_bit_cast(float, x);
}
// async global->LDS, 16 B per lane; LDS dst = wave-uniform base + lane*16
__device__ __forceinline__ void gl_lds16(const void* g, void* l) {
  __builtin_amdgcn_global_load_lds(
      (const __attribute__((address_space(1))) void*)g,
      (__attribute__((address_space(3))) void*)l, 16, 0, 0);
}

// ---------------------------------------------------------------------------
// K0: cast+transpose weights to bf16.
// ---------------------------------------------------------------------------
__global__ __launch_bounds__(256) void prep_weights(
    const float* __restrict__ Wk, const float* __restrict__ Wv,
    const float* __restrict__ Wg, const float* __restrict__ Wo,
    ushort_t* __restrict__ WkvT, ushort_t* __restrict__ WgT,
    ushort_t* __restrict__ WoT) {
  int t = blockIdx.x * 256 + threadIdx.x;       // 65536 threads
  int n = t >> 8, c = t & 255;
  if (t < 64 * 256) {
    float v = (n < 32) ? Wk[c * 32 + n] : Wv[c * 32 + (n - 32)];
    WkvT[t] = f2bf(v);
  }
  WgT[t] = f2bf(Wg[c * 256 + n]);
  WoT[t] = f2bf(Wo[c * 256 + n]);
}

// ---------------------------------------------------------------------------
// K1: LayerNorm -> xn (bf16) + per-block partial column sums (NO atomics).
// ---------------------------------------------------------------------------
__global__ __launch_bounds__(256) void ln_kernel(
    const float* __restrict__ x, const float* __restrict__ gamma,
    const float* __restrict__ beta, ushort_t* __restrict__ xn,
    float* __restrict__ xpart) {
  __shared__ float sacc[4][256];
  int b = blockIdx.x;                  // 2048
  int i = b & (I_DIM - 1);
  int sq = b >> 9;                     // 0..3
  int w = threadIdx.x >> 6;
  int lane = threadIdx.x & 63;

  float4 gv = *(const float4*)(gamma + lane * 4);
  float4 bv = *(const float4*)(beta + lane * 4);
  float p0 = 0.f, p1 = 0.f, p2 = 0.f, p3 = 0.f;

#pragma unroll 4
  for (int it = 0; it < 16; ++it) {
    int s = sq * 64 + w * 16 + it;
    size_t row = (size_t)s * I_DIM + i;
    float4 xv = *(const float4*)(x + row * 256 + lane * 4);
    float sum = xv.x + xv.y + xv.z + xv.w;
    float sq2 = xv.x*xv.x + xv.y*xv.y + xv.z*xv.z + xv.w*xv.w;
#pragma unroll
    for (int off = 32; off >= 1; off >>= 1) {
      sum += __shfl_xor(sum, off);
      sq2 += __shfl_xor(sq2, off);
    }
    float mu = sum * (1.f / 256.f);
    float rs = rsqrtf(sq2 * (1.f / 256.f) - mu * mu + 1e-5f);
    float y0 = (xv.x - mu) * rs * gv.x + bv.x;
    float y1 = (xv.y - mu) * rs * gv.y + bv.y;
    float y2 = (xv.z - mu) * rs * gv.z + bv.z;
    float y3 = (xv.w - mu) * rs * gv.w + bv.w;
    ushort4 o;
    o.x = f2bf(y0); o.y = f2bf(y1); o.z = f2bf(y2); o.w = f2bf(y3);
    *(ushort4*)(xn + row * 256 + lane * 4) = o;
    p0 += y0; p1 += y1; p2 += y2; p3 += y3;
  }
  sacc[w][lane * 4 + 0] = p0;
  sacc[w][lane * 4 + 1] = p1;
  sacc[w][lane * 4 + 2] = p2;
  sacc[w][lane * 4 + 3] = p3;
  __syncthreads();
  int tid = threadIdx.x;
  xpart[((size_t)sq * I_DIM + i) * 256 + tid] =
      sacc[0][tid] + sacc[1][tid] + sacc[2][tid] + sacc[3][tid];
}

// ---------------------------------------------------------------------------
// K2: Q[i][col] = mean_s(xn) @ Wq * (1/sqrt(D)); reduces the 4 partials.
// ---------------------------------------------------------------------------
__global__ __launch_bounds__(256) void q_kernel(
    const float* __restrict__ xpart, const float* __restrict__ Wq,
    float* __restrict__ Q) {
  int i = blockIdx.x, col = threadIdx.x;
  __shared__ float xr[256];
  float s = xpart[((size_t)0 * I_DIM + i) * 256 + col]
          + xpart[((size_t)1 * I_DIM + i) * 256 + col]
          + xpart[((size_t)2 * I_DIM + i) * 256 + col]
          + xpart[((size_t)3 * I_DIM + i) * 256 + col];
  xr[col] = s * (1.f / 256.f);
  __syncthreads();
  float acc = 0.f;
#pragma unroll 8
  for (int c = 0; c < 256; ++c) acc = fmaf(xr[c], Wq[c * 256 + col], acc);
  Q[i * 256 + col] = acc * 0.17677669529663687f;   // 1/sqrt(32)
}

// ---------------------------------------------------------------------------
// K3: KV[row][0:64] = xn[row] @ [Wk|Wv], bf16 output. 64-row tile, 4 waves.
// ---------------------------------------------------------------------------
__global__ __launch_bounds__(256) void kv_kernel(
    const ushort_t* __restrict__ xn, const ushort_t* __restrict__ WkvT,
    ushort_t* __restrict__ KVb) {
  __shared__ __attribute__((aligned(16))) ushort_t xs[64 * 264];
  __shared__ __attribute__((aligned(16))) ushort_t wt[64 * 264];
  int tid = threadIdx.x;
  int m0 = blockIdx.x * 64;

  const uint4* xg = (const uint4*)(xn + (size_t)m0 * 256);
#pragma unroll
  for (int j = 0; j < 8; ++j) {
    int idx = tid + j * 256;
    *(uint4*)(&xs[(idx >> 5) * 264 + (idx & 31) * 8]) = xg[idx];
  }
  const uint4* wg_ = (const uint4*)WkvT;
#pragma unroll
  for (int j = 0; j < 8; ++j) {
    int idx = tid + j * 256;
    *(uint4*)(&wt[(idx >> 5) * 264 + (idx & 31) * 8]) = wg_[idx];
  }
  __syncthreads();

  int w = tid >> 6, lane = tid & 63;
  int m15 = lane & 15, q = lane >> 4;
  f32x4 acc[4] = {};
#pragma unroll
  for (int k = 0; k < 8; ++k) {
    bf16x8 a = *(const bf16x8*)(&xs[(w * 16 + m15) * 264 + k * 32 + q * 8]);
#pragma unroll
    for (int nt = 0; nt < 4; ++nt) {
      bf16x8 bb = *(const bf16x8*)(&wt[(nt * 16 + m15) * 264 + k * 32 + q * 8]);
      acc[nt] = __builtin_amdgcn_mfma_f32_16x16x32_bf16(a, bb, acc[nt], 0, 0, 0);
    }
  }
#pragma unroll
  for (int nt = 0; nt < 4; ++nt)
#pragma unroll
    for (int r = 0; r < 4; ++r)
      KVb[(size_t)(m0 + w * 16 + q * 4 + r) * 64 + nt * 16 + m15] = f2bf(acc[nt][r]);
}

// ---------------------------------------------------------------------------
// K4: attention per residue i. K stays in registers; only V staged to LDS.
// ---------------------------------------------------------------------------
__global__ __launch_bounds__(256) void attn_kernel(
    const ushort_t* __restrict__ KVb, const float* __restrict__ Q,
    float* __restrict__ weighted) {
  __shared__ ushort_t Vs[256 * 36];    // stride 36 shorts: b64-aligned, 2-way banks
  __shared__ float sl[8 * 264];
  __shared__ float ql[256];
  int i = blockIdx.x, tid = threadIdx.x;

  ql[tid] = Q[i * 256 + tid];
  const uint4* src = (const uint4*)(KVb + ((size_t)tid * I_DIM + i) * 64);
  uint4 kr0 = src[0], kr1 = src[1], kr2 = src[2], kr3 = src[3];
#pragma unroll
  for (int j = 0; j < 4; ++j) {
    uint4 v = src[4 + j];
    *(ushort4*)(&Vs[tid * 36 + j * 8 + 0]) = *(ushort4*)&v.x;
    *(ushort4*)(&Vs[tid * 36 + j * 8 + 4]) = *(ushort4*)&v.z;
  }
  // unpack K to fp32
  ushort_t ks[32];
  *(uint4*)&ks[0] = kr0; *(uint4*)&ks[8] = kr1;
  *(uint4*)&ks[16] = kr2; *(uint4*)&ks[24] = kr3;
  float kf[32];
#pragma unroll
  for (int d = 0; d < 32; ++d) kf[d] = bf2f(ks[d]);
  __syncthreads();

#pragma unroll
  for (int h = 0; h < 8; ++h) {
    float sc = 0.f;
#pragma unroll
    for (int d = 0; d < 32; ++d) sc = fmaf(kf[d], ql[h * 32 + d], sc);
    sl[h * 264 + tid] = sc;
  }
  __syncthreads();

  int w = tid >> 6, lane = tid & 63;
#pragma unroll
  for (int hh = 0; hh < 2; ++hh) {
    int h = w * 2 + hh;
    float v0 = sl[h * 264 + lane], v1 = sl[h * 264 + lane + 64];
    float v2 = sl[h * 264 + lane + 128], v3 = sl[h * 264 + lane + 192];
    float m = fmaxf(fmaxf(v0, v1), fmaxf(v2, v3));
#pragma unroll
    for (int off = 32; off >= 1; off >>= 1) m = fmaxf(m, __shfl_xor(m, off));
    float e0 = __expf(v0 - m), e1 = __expf(v1 - m);
    float e2 = __expf(v2 - m), e3 = __expf(v3 - m);
    float ssum = e0 + e1 + e2 + e3;
#pragma unroll
    for (int off = 32; off >= 1; off >>= 1) ssum += __shfl_xor(ssum, off);
    float inv = 1.f / ssum;
    sl[h * 264 + lane] = e0 * inv;
    sl[h * 264 + lane + 64] = e1 * inv;
    sl[h * 264 + lane + 128] = e2 * inv;
    sl[h * 264 + lane + 192] = e3 * inv;
  }
  __syncthreads();

  int h = tid >> 5, d = tid & 31;
  float acc = 0.f;
#pragma unroll 4
  for (int t = 0; t < 256; ++t)
    acc = fmaf(sl[h * 264 + t], bf2f(Vs[t * 36 + d]), acc);
  weighted[i * 256 + tid] = acc;
}

// ---------------------------------------------------------------------------
// K5a: val = sigmoid(xn@Wg + bg) * weighted, bf16, IN PLACE over xn.
// Persistent-weight streaming GEMM: Wg (128 KB bf16) lives in LDS for the
// whole kernel; each wave hoists its 16 weight fragments to registers.
// 256 blocks (1/CU) x 512 thr; each block streams 16 tiles of 32 rows
// through a 2x16KB double buffer (stage t+1 || compute t, ONE barrier/iter).
// TRANSPOSED output orientation: mfma(Wfrag, xfrag) -> lane holds 4
// consecutive COLUMNS of one row -> ushort4 (8 B) coalesced val stores
// (fixes the 2x HBM write amplification seen with 2-B scatter stores).
// LDS: 128K + 2*16K = 160 KB exactly.
// ---------------------------------------------------------------------------
__global__ __launch_bounds__(512) void gate_val_kernel(
    ushort_t* xv,                       // xn in, val out (same buffer)
    const ushort_t* __restrict__ WgT, const float* __restrict__ weighted,
    const float* __restrict__ bg) {
  __shared__ __attribute__((aligned(16))) ushort_t Wl[256 * 256];   // 128 KB
  __shared__ __attribute__((aligned(16))) ushort_t Ab[2][32 * 256]; // 2x16 KB
  const int tid = threadIdx.x;
  const int w = tid >> 6, lane = tid & 63;
  const int m15 = lane & 15, q = lane >> 4;
  const size_t base = (size_t)blockIdx.x * 512;   // 512 rows per block

  // prologue: stage all of Wg (16/thread) + A tile 0 (2/thread)
#pragma unroll
  for (int it = 0; it < 16; ++it) {
    int L = it * 512 + tid;
    int n = L >> 5, u = L & 31;
    int us = (u & 24) | ((u & 7) ^ (n & 7));
    gl_lds16(WgT + (size_t)n * 256 + us * 8, &Wl[(it * 512 + w * 64) * 8]);
  }
#pragma unroll
  for (int it = 0; it < 2; ++it) {
    int L = it * 512 + tid;
    int r = L >> 5, u = L & 31;
    int us = (u & 24) | ((u & 7) ^ (r & 7));
    gl_lds16(xv + (base + r) * 256 + us * 8, &Ab[0][(it * 512 + w * 64) * 8]);
  }
  __syncthreads();

  // hoist Wg fragments: wave w owns output cols [w*32, w*32+32)
  bf16x8 wgf[2][8];
#pragma unroll
  for (int ct = 0; ct < 2; ++ct) {
    int n = w * 32 + ct * 16 + m15;
#pragma unroll
    for (int kk = 0; kk < 8; ++kk) {
      int ku = kk * 4 + q;
      int us = (ku & 24) | ((ku & 7) ^ (n & 7));
      wgf[ct][kk] = *(const bf16x8*)&Wl[n * 256 + us * 8];
    }
  }

#pragma unroll 1
  for (int t = 0; t < 16; ++t) {
    const int cur = t & 1;
    if (t < 15) {   // stage next A tile into the other buffer
#pragma unroll
      for (int it = 0; it < 2; ++it) {
        int L = it * 512 + tid;
        int r = L >> 5, u = L & 31;
        int us = (u & 24) | ((u & 7) ^ (r & 7));
        gl_lds16(xv + (base + (size_t)(t + 1) * 32 + r) * 256 + us * 8,
                 &Ab[cur ^ 1][(it * 512 + w * 64) * 8]);
      }
    }
    f32x4 acc[2][2];
    const f32x4 zero = {0.f, 0.f, 0.f, 0.f};
    acc[0][0] = zero; acc[0][1] = zero; acc[1][0] = zero; acc[1][1] = zero;
#pragma unroll
    for (int kk = 0; kk < 8; ++kk) {
      int ku = kk * 4 + q;
      int ub = (ku & 24) | ((ku & 7) ^ (m15 & 7));
      bf16x8 b0 = *(const bf16x8*)&Ab[cur][(0 * 16 + m15) * 256 + ub * 8];
      bf16x8 b1 = *(const bf16x8*)&Ab[cur][(1 * 16 + m15) * 256 + ub * 8];
#pragma unroll
      for (int ct = 0; ct < 2; ++ct) {
        acc[ct][0] = __builtin_amdgcn_mfma_f32_16x16x32_bf16(wgf[ct][kk], b0, acc[ct][0], 0, 0, 0);
        acc[ct][1] = __builtin_amdgcn_mfma_f32_16x16x32_bf16(wgf[ct][kk], b1, acc[ct][1], 0, 0, 0);
      }
    }
    // epilogue: lane holds val[row=base+t*32+mt*16+m15][cols w*32+ct*16+q*4 ..+3]
#pragma unroll
    for (int mt = 0; mt < 2; ++mt) {
      size_t row = base + (size_t)t * 32 + mt * 16 + m15;
      int i = (int)(row & (I_DIM - 1));
#pragma unroll
      for (int ct = 0; ct < 2; ++ct) {
        int col0 = w * 32 + ct * 16 + q * 4;
        float4 wv = *(const float4*)(weighted + (size_t)i * 256 + col0);
        float4 bgv = *(const float4*)(bg + col0);
        float p0 = acc[ct][mt][0] + bgv.x;
        float p1 = acc[ct][mt][1] + bgv.y;
        float p2 = acc[ct][mt][2] + bgv.z;
        float p3 = acc[ct][mt][3] + bgv.w;
        float g0 = 1.f / (1.f + __expf(-p0));
        float g1 = 1.f / (1.f + __expf(-p1));
        float g2 = 1.f / (1.f + __expf(-p2));
        float g3 = 1.f / (1.f + __expf(-p3));
        ushort4 o;
        o.x = f2bf(g0 * wv.x); o.y = f2bf(g1 * wv.y);
        o.z = f2bf(g2 * wv.z); o.w = f2bf(g3 * wv.w);
        *(ushort4*)(xv + row * 256 + col0) = o;
      }
    }
    __syncthreads();   // drains stage loads + all LDS reads of Ab[cur]
  }
}

// ---------------------------------------------------------------------------
// K5b: out = val @ Wo + bo (f32). Same persistent-weight streaming structure
// as K5a; transposed orientation -> float4 (16 B) coalesced out stores.
// ---------------------------------------------------------------------------
__global__ __launch_bounds__(512) void out_kernel(
    const ushort_t* __restrict__ val, const ushort_t* __restrict__ WoT,
    const float* __restrict__ bo, float* __restrict__ out) {
  __shared__ __attribute__((aligned(16))) ushort_t Wl[256 * 256];   // 128 KB
  __shared__ __attribute__((aligned(16))) ushort_t Ab[2][32 * 256]; // 2x16 KB
  const int tid = threadIdx.x;
  const int w = tid >> 6, lane = tid & 63;
  const int m15 = lane & 15, q = lane >> 4;
  const size_t base = (size_t)blockIdx.x * 512;

#pragma unroll
  for (int it = 0; it < 16; ++it) {
    int L = it * 512 + tid;
    int n = L >> 5, u = L & 31;
    int us = (u & 24) | ((u & 7) ^ (n & 7));
    gl_lds16(WoT + (size_t)n * 256 + us * 8, &Wl[(it * 512 + w * 64) * 8]);
  }
#pragma unroll
  for (int it = 0; it < 2; ++it) {
    int L = it * 512 + tid;
    int r = L >> 5, u = L & 31;
    int us = (u & 24) | ((u & 7) ^ (r & 7));
    gl_lds16(val + (base + r) * 256 + us * 8, &Ab[0][(it * 512 + w * 64) * 8]);
  }
  __syncthreads();

  bf16x8 wof[2][8];
#pragma unroll
  for (int ct = 0; ct < 2; ++ct) {
    int n = w * 32 + ct * 16 + m15;
#pragma unroll
    for (int kk = 0; kk < 8; ++kk) {
      int ku = kk * 4 + q;
      int us = (ku & 24) | ((ku & 7) ^ (n & 7));
      wof[ct][kk] = *(const bf16x8*)&Wl[n * 256 + us * 8];
    }
  }

#pragma unroll 1
  for (int t = 0; t < 16; ++t) {
    const int cur = t & 1;
    if (t < 15) {
#pragma unroll
      for (int it = 0; it < 2; ++it) {
        int L = it * 512 + tid;
        int r = L >> 5, u = L & 31;
        int us = (u & 24) | ((u & 7) ^ (r & 7));
        gl_lds16(val + (base + (size_t)(t + 1) * 32 + r) * 256 + us * 8,
                 &Ab[cur ^ 1][(it * 512 + w * 64) * 8]);
      }
    }
    f32x4 acc[2][2];
    const f32x4 zero = {0.f, 0.f, 0.f, 0.f};
    acc[0][0] = zero; acc[0][1] = zero; acc[1][0] = zero; acc[1][1] = zero;
#pragma unroll
    for (int kk = 0; kk < 8; ++kk) {
      int ku = kk * 4 + q;
      int ub = (ku & 24) | ((ku & 7) ^ (m15 & 7));
      bf16x8 b0 = *(const bf16x8*)&Ab[cur][(0 * 16 + m15) * 256 + ub * 8];
      bf16x8 b1 = *(const bf16x8*)&Ab[cur][(1 * 16 + m15) * 256 + ub * 8];
#pragma unroll
      for (int ct = 0; ct < 2; ++ct) {
        acc[ct][0] = __builtin_amdgcn_mfma_f32_16x16x32_bf16(wof[ct][kk], b0, acc[ct][0], 0, 0, 0);
        acc[ct][1] = __builtin_amdgcn_mfma_f32_16x16x32_bf16(wof[ct][kk], b1, acc[ct][1], 0, 0, 0);
      }
    }
#pragma unroll
    for (int mt = 0; mt < 2; ++mt) {
      size_t row = base + (size_t)t * 32 + mt * 16 + m15;
#pragma unroll
      for (int ct = 0; ct < 2; ++ct) {
        int col0 = w * 32 + ct * 16 + q * 4;
        float4 bov = *(const float4*)(bo + col0);
        float4 ov;
        ov.x = acc[ct][mt][0] + bov.x;
        ov.y = acc[ct][mt][1] + bov.y;
        ov.z = acc[ct][mt][2] + bov.z;
        ov.w = acc[ct][mt][3] + bov.w;
        *(float4*)(out + row * 256 + col0) = ov;
      }
    }
    __syncthreads();
  }
}

// ---------------------------------------------------------------------------
extern "C" void kernel_launch(void* const* d_in, const int* in_sizes, int n_in,
                              void* d_out, int out_size, void* d_ws, size_t ws_size,
                              hipStream_t stream) {
  const float* msa = (const float*)d_in[0];
  const float* gam = (const float*)d_in[1];
  const float* bet = (const float*)d_in[2];
  const float* Wq  = (const float*)d_in[3];
  const float* Wk  = (const float*)d_in[4];
  const float* Wv  = (const float*)d_in[5];
  const float* Wg  = (const float*)d_in[6];
  const float* bg  = (const float*)d_in[7];
  const float* Wo  = (const float*)d_in[8];
  const float* bo  = (const float*)d_in[9];
  float* out = (float*)d_out;

  char* ws = (char*)d_ws;
  ushort_t* xn     = (ushort_t*)ws;                    // 67,108,864 B (xn, then val in-place)
  float* xpart     = (float*)(ws + 67108864);          //  2,097,152 B
  float* Q         = (float*)(ws + 69206016);          //    524,288 B
  ushort_t* KVb    = (ushort_t*)(ws + 69730304);       // 16,777,216 B
  float* weighted  = (float*)(ws + 86507520);          //    524,288 B
  ushort_t* WkvT   = (ushort_t*)(ws + 87031808);       //     32,768 B
  ushort_t* WgT    = (ushort_t*)(ws + 87064576);       //    131,072 B
  ushort_t* WoT    = (ushort_t*)(ws + 87195648);       //    131,072 B

  prep_weights<<<256, 256, 0, stream>>>(Wk, Wv, Wg, Wo, WkvT, WgT, WoT);
  ln_kernel<<<2048, 256, 0, stream>>>(msa, gam, bet, xn, xpart);
  q_kernel<<<512, 256, 0, stream>>>(xpart, Wq, Q);
  kv_kernel<<<2048, 256, 0, stream>>>(xn, WkvT, KVb);
  attn_kernel<<<512, 256, 0, stream>>>(KVb, Q, weighted);
  gate_val_kernel<<<256, 512, 0, stream>>>(xn, WgT, weighted, bg);
  out_kernel<<<256, 512, 0, stream>>>(xn, WoT, bo, out);
}

// Round 3
// 353.893 us; speedup vs baseline: 1.1101x; 1.0504x over previous
//
#include <hip/hip_runtime.h>
#include <hip/hip_bf16.h>

#define S_DIM 256
#define I_DIM 512
#define NROWS (S_DIM * I_DIM)  // 131072

using bf16x8 = __attribute__((ext_vector_type(8))) short;
using f32x4  = __attribute__((ext_vector_type(4))) float;
typedef unsigned short ushort_t;

__device__ __forceinline__ unsigned short f2bf(float f) {
  unsigned int u = __builtin_bit_cast(unsigned int, f);
  u += 0x7fffu + ((u >> 16) & 1u);   // RNE
  return (unsigned short)(u >> 16);
}
__device__ __forceinline__ float bf2f(unsigned short u) {
  unsigned int x = ((unsigned int)u) << 16;
  return __builtin_bit_cast(float, x);
}
// async global->LDS, 16 B per lane; LDS dst = wave-uniform base + lane*16
__device__ __forceinline__ void gl_lds16(const void* g, void* l) {
  __builtin_amdgcn_global_load_lds(
      (const __attribute__((address_space(1))) void*)g,
      (__attribute__((address_space(3))) void*)l, 16, 0, 0);
}

// ---------------------------------------------------------------------------
// K0: cast+transpose weights to bf16.
// ---------------------------------------------------------------------------
__global__ __launch_bounds__(256) void prep_weights(
    const float* __restrict__ Wk, const float* __restrict__ Wv,
    const float* __restrict__ Wg, const float* __restrict__ Wo,
    ushort_t* __restrict__ WkvT, ushort_t* __restrict__ WgT,
    ushort_t* __restrict__ WoT) {
  int t = blockIdx.x * 256 + threadIdx.x;       // 65536 threads
  int n = t >> 8, c = t & 255;
  if (t < 64 * 256) {
    float v = (n < 32) ? Wk[c * 32 + n] : Wv[c * 32 + (n - 32)];
    WkvT[t] = f2bf(v);
  }
  WgT[t] = f2bf(Wg[c * 256 + n]);
  WoT[t] = f2bf(Wo[c * 256 + n]);
}

// ---------------------------------------------------------------------------
// K1: LayerNorm -> xn (bf16) + partial column sums + FUSED K/V projection.
// Block b: i = b&511, sq = b>>9; wave w handles s = sq*64 + w*16 + it.
// The 64 LN'd rows (bf16, post-rounding) are dropped into a kv-layout LDS
// tile; the kv MFMA body then runs in-block, eliminating kv_kernel's 64 MB
// re-read of xn. KVb row mapping: global row = (sq*64 + local)*512 + i.
// LDS: sacc 4K + xs 33K + wt 33K = 70 KB -> 2 blocks/CU.
// ---------------------------------------------------------------------------
__global__ __launch_bounds__(256) void ln_kv_kernel(
    const float* __restrict__ x, const float* __restrict__ gamma,
    const float* __restrict__ beta, const ushort_t* __restrict__ WkvT,
    ushort_t* __restrict__ xn, float* __restrict__ xpart,
    ushort_t* __restrict__ KVb) {
  __shared__ float sacc[4][256];
  __shared__ __attribute__((aligned(16))) ushort_t xs[64 * 264];
  __shared__ __attribute__((aligned(16))) ushort_t wt[64 * 264];
  int b = blockIdx.x;                  // 2048
  int i = b & (I_DIM - 1);
  int sq = b >> 9;                     // 0..3
  int tid = threadIdx.x;
  int w = tid >> 6;
  int lane = tid & 63;

  // stage WkvT (32 KB, L2-hot) into kv fragment layout
  const uint4* wg_ = (const uint4*)WkvT;
#pragma unroll
  for (int j = 0; j < 8; ++j) {
    int idx = tid + j * 256;
    *(uint4*)(&wt[(idx >> 5) * 264 + (idx & 31) * 8]) = wg_[idx];
  }

  float4 gv = *(const float4*)(gamma + lane * 4);
  float4 bv = *(const float4*)(beta + lane * 4);
  float p0 = 0.f, p1 = 0.f, p2 = 0.f, p3 = 0.f;

#pragma unroll 4
  for (int it = 0; it < 16; ++it) {
    int s = sq * 64 + w * 16 + it;
    size_t row = (size_t)s * I_DIM + i;
    float4 xv = *(const float4*)(x + row * 256 + lane * 4);
    float sum = xv.x + xv.y + xv.z + xv.w;
    float sq2 = xv.x*xv.x + xv.y*xv.y + xv.z*xv.z + xv.w*xv.w;
#pragma unroll
    for (int off = 32; off >= 1; off >>= 1) {
      sum += __shfl_xor(sum, off);
      sq2 += __shfl_xor(sq2, off);
    }
    float mu = sum * (1.f / 256.f);
    float rs = rsqrtf(sq2 * (1.f / 256.f) - mu * mu + 1e-5f);
    float y0 = (xv.x - mu) * rs * gv.x + bv.x;
    float y1 = (xv.y - mu) * rs * gv.y + bv.y;
    float y2 = (xv.z - mu) * rs * gv.z + bv.z;
    float y3 = (xv.w - mu) * rs * gv.w + bv.w;
    ushort4 o;
    o.x = f2bf(y0); o.y = f2bf(y1); o.z = f2bf(y2); o.w = f2bf(y3);
    *(ushort4*)(xn + row * 256 + lane * 4) = o;
    *(ushort4*)(&xs[(w * 16 + it) * 264 + lane * 4]) = o;   // same rounded bits
    p0 += y0; p1 += y1; p2 += y2; p3 += y3;
  }
  sacc[w][lane * 4 + 0] = p0;
  sacc[w][lane * 4 + 1] = p1;
  sacc[w][lane * 4 + 2] = p2;
  sacc[w][lane * 4 + 3] = p3;
  __syncthreads();
  xpart[((size_t)sq * I_DIM + i) * 256 + tid] =
      sacc[0][tid] + sacc[1][tid] + sacc[2][tid] + sacc[3][tid];

  // ---- fused K/V projection (kv_kernel body, row-remapped) ----
  int m15 = lane & 15, q = lane >> 4;
  f32x4 acc[4] = {};
#pragma unroll
  for (int k = 0; k < 8; ++k) {
    bf16x8 a = *(const bf16x8*)(&xs[(w * 16 + m15) * 264 + k * 32 + q * 8]);
#pragma unroll
    for (int nt = 0; nt < 4; ++nt) {
      bf16x8 bb = *(const bf16x8*)(&wt[(nt * 16 + m15) * 264 + k * 32 + q * 8]);
      acc[nt] = __builtin_amdgcn_mfma_f32_16x16x32_bf16(a, bb, acc[nt], 0, 0, 0);
    }
  }
#pragma unroll
  for (int nt = 0; nt < 4; ++nt)
#pragma unroll
    for (int r = 0; r < 4; ++r) {
      int s = sq * 64 + w * 16 + q * 4 + r;
      KVb[((size_t)s * I_DIM + i) * 64 + nt * 16 + m15] = f2bf(acc[nt][r]);
    }
}

// ---------------------------------------------------------------------------
// K2: Q[i][col] = mean_s(xn) @ Wq * (1/sqrt(D)); reduces the 4 partials.
// ---------------------------------------------------------------------------
__global__ __launch_bounds__(256) void q_kernel(
    const float* __restrict__ xpart, const float* __restrict__ Wq,
    float* __restrict__ Q) {
  int i = blockIdx.x, col = threadIdx.x;
  __shared__ float xr[256];
  float s = xpart[((size_t)0 * I_DIM + i) * 256 + col]
          + xpart[((size_t)1 * I_DIM + i) * 256 + col]
          + xpart[((size_t)2 * I_DIM + i) * 256 + col]
          + xpart[((size_t)3 * I_DIM + i) * 256 + col];
  xr[col] = s * (1.f / 256.f);
  __syncthreads();
  float acc = 0.f;
#pragma unroll 8
  for (int c = 0; c < 256; ++c) acc = fmaf(xr[c], Wq[c * 256 + col], acc);
  Q[i * 256 + col] = acc * 0.17677669529663687f;   // 1/sqrt(32)
}

// ---------------------------------------------------------------------------
// K4: attention per residue i. K stays in registers; only V staged to LDS.
// ---------------------------------------------------------------------------
__global__ __launch_bounds__(256) void attn_kernel(
    const ushort_t* __restrict__ KVb, const float* __restrict__ Q,
    float* __restrict__ weighted) {
  __shared__ ushort_t Vs[256 * 36];    // stride 36 shorts: b64-aligned, 2-way banks
  __shared__ float sl[8 * 264];
  __shared__ float ql[256];
  int i = blockIdx.x, tid = threadIdx.x;

  ql[tid] = Q[i * 256 + tid];
  const uint4* src = (const uint4*)(KVb + ((size_t)tid * I_DIM + i) * 64);
  uint4 kr0 = src[0], kr1 = src[1], kr2 = src[2], kr3 = src[3];
#pragma unroll
  for (int j = 0; j < 4; ++j) {
    uint4 v = src[4 + j];
    *(ushort4*)(&Vs[tid * 36 + j * 8 + 0]) = *(ushort4*)&v.x;
    *(ushort4*)(&Vs[tid * 36 + j * 8 + 4]) = *(ushort4*)&v.z;
  }
  // unpack K to fp32
  ushort_t ks[32];
  *(uint4*)&ks[0] = kr0; *(uint4*)&ks[8] = kr1;
  *(uint4*)&ks[16] = kr2; *(uint4*)&ks[24] = kr3;
  float kf[32];
#pragma unroll
  for (int d = 0; d < 32; ++d) kf[d] = bf2f(ks[d]);
  __syncthreads();

#pragma unroll
  for (int h = 0; h < 8; ++h) {
    float sc = 0.f;
#pragma unroll
    for (int d = 0; d < 32; ++d) sc = fmaf(kf[d], ql[h * 32 + d], sc);
    sl[h * 264 + tid] = sc;
  }
  __syncthreads();

  int w = tid >> 6, lane = tid & 63;
#pragma unroll
  for (int hh = 0; hh < 2; ++hh) {
    int h = w * 2 + hh;
    float v0 = sl[h * 264 + lane], v1 = sl[h * 264 + lane + 64];
    float v2 = sl[h * 264 + lane + 128], v3 = sl[h * 264 + lane + 192];
    float m = fmaxf(fmaxf(v0, v1), fmaxf(v2, v3));
#pragma unroll
    for (int off = 32; off >= 1; off >>= 1) m = fmaxf(m, __shfl_xor(m, off));
    float e0 = __expf(v0 - m), e1 = __expf(v1 - m);
    float e2 = __expf(v2 - m), e3 = __expf(v3 - m);
    float ssum = e0 + e1 + e2 + e3;
#pragma unroll
    for (int off = 32; off >= 1; off >>= 1) ssum += __shfl_xor(ssum, off);
    float inv = 1.f / ssum;
    sl[h * 264 + lane] = e0 * inv;
    sl[h * 264 + lane + 64] = e1 * inv;
    sl[h * 264 + lane + 128] = e2 * inv;
    sl[h * 264 + lane + 192] = e3 * inv;
  }
  __syncthreads();

  int h = tid >> 5, d = tid & 31;
  float acc = 0.f;
#pragma unroll 4
  for (int t = 0; t < 256; ++t)
    acc = fmaf(sl[h * 264 + t], bf2f(Vs[t * 36 + d]), acc);
  weighted[i * 256 + tid] = acc;
}

// ---------------------------------------------------------------------------
// K5: FUSED  val = sigmoid(xn@Wg+bg)*weighted ; out = val@Wo + bo.
// Weights are loaded fragment-wise straight from L2 into registers (wgf/wof,
// 64 VGPR each) -- no LDS weight staging. Per 32-row tile:
//   stage A(t+1) -> GEMM1 -> eplg1 (sigmoid*weighted -> valT LDS, swizzled)
//   -> lgkm-only barrier (A-prefetch stays in flight) -> GEMM2 (valT@Wo)
//   -> float4 out stores -> full __syncthreads (drains stage).
// val never touches HBM (saves 128 MB vs the split version).
// LDS: Ab 2x16K + valT 16K = 48 KB. 256 blocks x 512 thr (8 waves, 1/CU).
// ---------------------------------------------------------------------------
__global__ __launch_bounds__(512) void gate_out_kernel(
    const ushort_t* __restrict__ xn, const ushort_t* __restrict__ WgT,
    const ushort_t* __restrict__ WoT, const float* __restrict__ weighted,
    const float* __restrict__ bg, const float* __restrict__ bo,
    float* __restrict__ out) {
  __shared__ __attribute__((aligned(16))) ushort_t Ab[2][32 * 256]; // 2x16 KB
  __shared__ __attribute__((aligned(16))) ushort_t valT[32 * 256];  // 16 KB
  const int tid = threadIdx.x;
  const int w = tid >> 6, lane = tid & 63;
  const int m15 = lane & 15, q = lane >> 4;
  const size_t base = (size_t)blockIdx.x * 512;   // 512 rows per block

  // hoist weight fragments straight from global (L2-resident, 16 B aligned)
  bf16x8 wgf[2][8], wof[2][8];
#pragma unroll
  for (int ct = 0; ct < 2; ++ct) {
    int n = w * 32 + ct * 16 + m15;
#pragma unroll
    for (int kk = 0; kk < 8; ++kk) {
      int ku = kk * 4 + q;
      wgf[ct][kk] = *(const bf16x8*)(WgT + (size_t)n * 256 + ku * 8);
      wof[ct][kk] = *(const bf16x8*)(WoT + (size_t)n * 256 + ku * 8);
    }
  }
  // bias vectors for this wave's 32 output cols (2 ct x float4)
  float4 bgv[2], bov[2];
#pragma unroll
  for (int ct = 0; ct < 2; ++ct) {
    int col0 = w * 32 + ct * 16 + q * 4;
    bgv[ct] = *(const float4*)(bg + col0);
    bov[ct] = *(const float4*)(bo + col0);
  }

  // stage A tile 0
#pragma unroll
  for (int it = 0; it < 2; ++it) {
    int L = it * 512 + tid;
    int r = L >> 5, u = L & 31;
    int us = (u & 24) | ((u & 7) ^ (r & 7));
    gl_lds16(xn + (base + r) * 256 + us * 8, &Ab[0][(it * 512 + w * 64) * 8]);
  }
  __syncthreads();

#pragma unroll 1
  for (int t = 0; t < 16; ++t) {
    const int cur = t & 1;
    if (t < 15) {   // prefetch next A tile
#pragma unroll
      for (int it = 0; it < 2; ++it) {
        int L = it * 512 + tid;
        int r = L >> 5, u = L & 31;
        int us = (u & 24) | ((u & 7) ^ (r & 7));
        gl_lds16(xn + (base + (size_t)(t + 1) * 32 + r) * 256 + us * 8,
                 &Ab[cur ^ 1][(it * 512 + w * 64) * 8]);
      }
    }

    // ---- GEMM1: pre-gate = x_tile @ Wg ----
    f32x4 acc1[2][2];
    const f32x4 zero = {0.f, 0.f, 0.f, 0.f};
    acc1[0][0] = zero; acc1[0][1] = zero; acc1[1][0] = zero; acc1[1][1] = zero;
#pragma unroll
    for (int kk = 0; kk < 8; ++kk) {
      int ku = kk * 4 + q;
      int ub = (ku & 24) | ((ku & 7) ^ (m15 & 7));
      bf16x8 b0 = *(const bf16x8*)&Ab[cur][(0 * 16 + m15) * 256 + ub * 8];
      bf16x8 b1 = *(const bf16x8*)&Ab[cur][(1 * 16 + m15) * 256 + ub * 8];
#pragma unroll
      for (int ct = 0; ct < 2; ++ct) {
        acc1[ct][0] = __builtin_amdgcn_mfma_f32_16x16x32_bf16(wgf[ct][kk], b0, acc1[ct][0], 0, 0, 0);
        acc1[ct][1] = __builtin_amdgcn_mfma_f32_16x16x32_bf16(wgf[ct][kk], b1, acc1[ct][1], 0, 0, 0);
      }
    }

    // ---- epilogue 1: sigmoid gate * weighted -> valT (swizzled LDS) ----
#pragma unroll
    for (int mt = 0; mt < 2; ++mt) {
      int rloc = mt * 16 + m15;
      int i = t * 32 + rloc;           // row & 511 (base is a multiple of 512)
#pragma unroll
      for (int ct = 0; ct < 2; ++ct) {
        int col0 = w * 32 + ct * 16 + q * 4;
        float4 wv = *(const float4*)(weighted + (size_t)i * 256 + col0);
        float pz0 = acc1[ct][mt][0] + bgv[ct].x;
        float pz1 = acc1[ct][mt][1] + bgv[ct].y;
        float pz2 = acc1[ct][mt][2] + bgv[ct].z;
        float pz3 = acc1[ct][mt][3] + bgv[ct].w;
        float g0 = 1.f / (1.f + __expf(-pz0));
        float g1 = 1.f / (1.f + __expf(-pz1));
        float g2 = 1.f / (1.f + __expf(-pz2));
        float g3 = 1.f / (1.f + __expf(-pz3));
        ushort4 o;
        o.x = f2bf(g0 * wv.x); o.y = f2bf(g1 * wv.y);
        o.z = f2bf(g2 * wv.z); o.w = f2bf(g3 * wv.w);
        int u = col0 >> 3;
        int us = (u & 24) | ((u & 7) ^ (rloc & 7));
        *(ushort4*)(&valT[rloc * 256 + us * 8 + (col0 & 7)]) = o;
      }
    }

    // light barrier: wait LDS writes only; A-prefetch (vmcnt) stays in flight
    __builtin_amdgcn_sched_barrier(0);
    asm volatile("s_waitcnt lgkmcnt(0)" ::: "memory");
    __builtin_amdgcn_s_barrier();
    __builtin_amdgcn_sched_barrier(0);

    // ---- GEMM2: out_tile = valT @ Wo ----
    f32x4 acc2[2][2];
    acc2[0][0] = zero; acc2[0][1] = zero; acc2[1][0] = zero; acc2[1][1] = zero;
#pragma unroll
    for (int kk = 0; kk < 8; ++kk) {
      int ku = kk * 4 + q;
      int ub = (ku & 24) | ((ku & 7) ^ (m15 & 7));
      bf16x8 b0 = *(const bf16x8*)&valT[(0 * 16 + m15) * 256 + ub * 8];
      bf16x8 b1 = *(const bf16x8*)&valT[(1 * 16 + m15) * 256 + ub * 8];
#pragma unroll
      for (int ct = 0; ct < 2; ++ct) {
        acc2[ct][0] = __builtin_amdgcn_mfma_f32_16x16x32_bf16(wof[ct][kk], b0, acc2[ct][0], 0, 0, 0);
        acc2[ct][1] = __builtin_amdgcn_mfma_f32_16x16x32_bf16(wof[ct][kk], b1, acc2[ct][1], 0, 0, 0);
      }
    }

    // ---- epilogue 2: out = acc2 + bo (coalesced float4) ----
#pragma unroll
    for (int mt = 0; mt < 2; ++mt) {
      size_t row = base + (size_t)t * 32 + mt * 16 + m15;
#pragma unroll
      for (int ct = 0; ct < 2; ++ct) {
        int col0 = w * 32 + ct * 16 + q * 4;
        float4 ov;
        ov.x = acc2[ct][mt][0] + bov[ct].x;
        ov.y = acc2[ct][mt][1] + bov[ct].y;
        ov.z = acc2[ct][mt][2] + bov[ct].z;
        ov.w = acc2[ct][mt][3] + bov[ct].w;
        *(float4*)(out + row * 256 + col0) = ov;
      }
    }

    __syncthreads();   // drains A-prefetch + protects valT/Ab reuse
  }
}

// ---------------------------------------------------------------------------
extern "C" void kernel_launch(void* const* d_in, const int* in_sizes, int n_in,
                              void* d_out, int out_size, void* d_ws, size_t ws_size,
                              hipStream_t stream) {
  const float* msa = (const float*)d_in[0];
  const float* gam = (const float*)d_in[1];
  const float* bet = (const float*)d_in[2];
  const float* Wq  = (const float*)d_in[3];
  const float* Wk  = (const float*)d_in[4];
  const float* Wv  = (const float*)d_in[5];
  const float* Wg  = (const float*)d_in[6];
  const float* bg  = (const float*)d_in[7];
  const float* Wo  = (const float*)d_in[8];
  const float* bo  = (const float*)d_in[9];
  float* out = (float*)d_out;

  char* ws = (char*)d_ws;
  ushort_t* xn     = (ushort_t*)ws;                    // 67,108,864 B
  float* xpart     = (float*)(ws + 67108864);          //  2,097,152 B
  float* Q         = (float*)(ws + 69206016);          //    524,288 B
  ushort_t* KVb    = (ushort_t*)(ws + 69730304);       // 16,777,216 B
  float* weighted  = (float*)(ws + 86507520);          //    524,288 B
  ushort_t* WkvT   = (ushort_t*)(ws + 87031808);       //     32,768 B
  ushort_t* WgT    = (ushort_t*)(ws + 87064576);       //    131,072 B
  ushort_t* WoT    = (ushort_t*)(ws + 87195648);       //    131,072 B

  prep_weights<<<256, 256, 0, stream>>>(Wk, Wv, Wg, Wo, WkvT, WgT, WoT);
  ln_kv_kernel<<<2048, 256, 0, stream>>>(msa, gam, bet, WkvT, xn, xpart, KVb);
  q_kernel<<<512, 256, 0, stream>>>(xpart, Wq, Q);
  attn_kernel<<<512, 256, 0, stream>>>(KVb, Q, weighted);
  gate_out_kernel<<<256, 512, 0, stream>>>(xn, WgT, WoT, weighted, bg, bo, out);
}